// Round 1
// baseline (1293.897 us; speedup 1.0000x reference)
//
#include <hip/hip_runtime.h>
#include <math.h>

#define B_ 8
#define C_ 80
#define H_ 128
#define W_ 128
#define K_ 100
#define MAXOBJS_ 128
#define NGT_ 256
#define HW_ (H_*W_)
#define CHW_ (C_*H_*W_)
#define TOT_ (B_*CHW_)
#define NBINS_ 4096
#define BCAP_ 4096
#define DCAP_ 128

// ---- ws layout (bytes) ----
// [0,64)        double accum[8]: 0 neg_base, 1 pos_sum, 2 neg_delta, 3 wh_num, 4 off_num, 5 mask_sum
// [64,128)      int misc[16]: 0 num_pos
// [128,131200)  u32 hist[8][4096]
// [131200..]    u32 thrbin[8], cntab[8], cntA[8], cntB[8]
// [131328..]    float defv[8*128]; int defi[8*128]; float borv[8*4096]; int bori[8*4096]
#define OFF_THR    131200
#define OFF_CNTAB  131232
#define OFF_CNTA   131264
#define OFF_CNTB   131296
#define OFF_DEFV   131328
#define OFF_DEFI   135424
#define OFF_BORV   139520
#define OFF_BORI   270592
#define ZERO_BYTES 131328

__device__ __forceinline__ unsigned skey(float x){
    unsigned u = __float_as_uint(x);
    return (u & 0x80000000u) ? ~u : (u | 0x80000000u);
}

__device__ __forceinline__ bool is_peak(const float* __restrict__ hm, int idx, float v){
    int w = idx & (W_-1);
    int h = (idx >> 7) & (H_-1);
    bool peak = true;
    #pragma unroll
    for(int dy=-1; dy<=1; ++dy){
        int hh = h + dy;
        if(hh < 0 || hh >= H_) continue;
        #pragma unroll
        for(int dx=-1; dx<=1; ++dx){
            if(dy==0 && dx==0) continue;
            int ww = w + dx;
            if(ww < 0 || ww >= W_) continue;
            peak = peak && (v >= __ldg(&hm[idx + dy*W_ + dx]));
        }
    }
    return peak;
}

// Pass 1: peak histogram + focal-loss negative base (gt = hm_target, no iou)
__global__ __launch_bounds__(256) void k_main(const float* __restrict__ hm,
                                              const float* __restrict__ hmt,
                                              unsigned* __restrict__ hist,
                                              double* __restrict__ accum){
    int idx = blockIdx.x*256 + threadIdx.x;
    float v = hm[idx];
    int b = idx / CHW_;
    if(is_peak(hm, idx, v)){
        atomicAdd(&hist[b*NBINS_ + (skey(v)>>20)], 1u);
    }
    float p = 1.f/(1.f + __expf(-v));
    p = fminf(fmaxf(p, 1e-4f), 1.f - 1e-4f);
    float gt = hmt[idx];
    float q = 1.f - gt;
    float q2 = q*q;
    float term = __logf(1.f - p) * p * p * q2 * q2;
    __shared__ float red[256];
    red[threadIdx.x] = term;
    __syncthreads();
    for(int s=128; s>0; s>>=1){
        if(threadIdx.x < s) red[threadIdx.x] += red[threadIdx.x+s];
        __syncthreads();
    }
    if(threadIdx.x == 0) atomicAdd(&accum[0], (double)red[0]);
}

// Find per-batch threshold bin: smallest set of top bins with cum count >= K
__global__ void k_thresh(const unsigned* __restrict__ hist,
                         unsigned* __restrict__ thrbin, unsigned* __restrict__ cntab){
    __shared__ unsigned lh[NBINS_];
    int b = blockIdx.x;
    for(int i=threadIdx.x; i<NBINS_; i+=blockDim.x) lh[i] = hist[b*NBINS_+i];
    __syncthreads();
    if(threadIdx.x == 0){
        unsigned cum = 0, thr = 0;
        for(int bin=NBINS_-1; bin>=0; --bin){
            unsigned c = lh[bin];
            if(cum + c >= K_){ thr = (unsigned)bin; break; }
            cum += c;
        }
        thrbin[b] = thr;
        cntab[b]  = cum;
    }
}

// Pass 2: collect definite (> thr bin) and borderline (== thr bin) peak candidates
__global__ __launch_bounds__(256) void k_collect(const float* __restrict__ hm,
                                                 const unsigned* __restrict__ thrbin,
                                                 unsigned* __restrict__ cntA, unsigned* __restrict__ cntB,
                                                 float* __restrict__ defv, int* __restrict__ defi,
                                                 float* __restrict__ borv, int* __restrict__ bori){
    int idx = blockIdx.x*256 + threadIdx.x;
    float v = hm[idx];
    if(!is_peak(hm, idx, v)) return;
    int b = idx / CHW_;
    unsigned bin = skey(v) >> 20;
    unsigned thr = thrbin[b];
    if(bin > thr){
        unsigned p = atomicAdd(&cntA[b], 1u);
        if(p < DCAP_){ defv[b*DCAP_+p] = v; defi[b*DCAP_+p] = idx - b*CHW_; }
    } else if(bin == thr){
        unsigned p = atomicAdd(&cntB[b], 1u);
        if(p < BCAP_){ borv[b*BCAP_+p] = v; bori[b*BCAP_+p] = idx - b*CHW_; }
    }
}

// Per-batch: finalize top-K set, decode boxes, IoU vs GT, focal fixup at scattered points
__global__ __launch_bounds__(256) void k_batch(const float* __restrict__ hm,
                                               const float* __restrict__ hmt,
                                               const float* __restrict__ wh,
                                               const float* __restrict__ reg,
                                               const float* __restrict__ tbox,
                                               const int* __restrict__ tbid,
                                               const unsigned* __restrict__ cntA,
                                               const unsigned* __restrict__ cntB,
                                               const float* __restrict__ defv, const int* __restrict__ defi,
                                               const float* __restrict__ borv, const int* __restrict__ bori,
                                               double* __restrict__ accum, int* __restrict__ misc){
    int b = blockIdx.x;
    int tid = threadIdx.x;
    __shared__ float sbox[NGT_][4];
    __shared__ int   sbid[NGT_];
    __shared__ float sv[BCAP_];
    __shared__ int   si[BCAP_];
    __shared__ float rv[256];
    __shared__ int   ri[256];
    __shared__ int   sel[K_];

    unsigned nAu = cntA[b];
    int nA = (nAu > (unsigned)DCAP_) ? DCAP_ : (int)nAu;
    if(nA > K_) nA = K_;
    unsigned nBu = cntB[b];
    int nB = (nBu > (unsigned)BCAP_) ? BCAP_ : (int)nBu;
    int m = K_ - nA;
    if(m > nB) m = nB;
    if(m < 0)  m = 0;

    for(int i=tid; i<nB; i+=256){ sv[i] = borv[b*BCAP_+i]; si[i] = bori[b*BCAP_+i]; }
    for(int i=tid; i<NGT_; i+=256){
        sbox[i][0] = tbox[i*4+0]; sbox[i][1] = tbox[i*4+1];
        sbox[i][2] = tbox[i*4+2]; sbox[i][3] = tbox[i*4+3];
        sbid[i] = tbid[i];
    }
    __syncthreads();

    // iterative argmax to pick top-m from borderline bin
    for(int it=0; it<m; ++it){
        float bv = -INFINITY; int bi = -1;
        for(int i=tid; i<nB; i+=256){
            if(sv[i] > bv){ bv = sv[i]; bi = i; }
        }
        rv[tid] = bv; ri[tid] = bi;
        __syncthreads();
        for(int st=128; st>0; st>>=1){
            if(tid < st){
                if(rv[tid+st] > rv[tid]){ rv[tid] = rv[tid+st]; ri[tid] = ri[tid+st]; }
            }
            __syncthreads();
        }
        if(tid == 0){ sel[it] = si[ri[0]]; sv[ri[0]] = -INFINITY; }
        __syncthreads();
    }
    for(int i=tid; i<nA; i+=256) sel[m+i] = defi[b*DCAP_+i];
    __syncthreads();

    int nsel = m + nA;
    for(int k=tid; k<nsel; k+=256){
        int idx = sel[k];
        int cls = idx / HW_;
        int sp  = idx - cls*HW_;
        int yi  = sp >> 7;
        int xi  = sp & (W_-1);
        float r0 = reg[(b*2+0)*HW_ + sp];
        float r1 = reg[(b*2+1)*HW_ + sp];
        float w0 = wh[(b*2+0)*HW_ + sp];
        float w1 = wh[(b*2+1)*HW_ + sp];
        float xs = (float)xi + r0;
        float ys = (float)yi + r1;
        float x1 = xs - w0*0.5f, y1 = ys - w1*0.5f;
        float x2 = xs + w0*0.5f, y2 = ys + w1*0.5f;
        float a1 = fmaxf(x2-x1, 0.f) * fmaxf(y2-y1, 0.f);
        float best = 0.f;
        for(int g=0; g<NGT_; ++g){
            if(sbid[g] != b) continue;
            float gx1 = sbox[g][0], gy1 = sbox[g][1], gx2 = sbox[g][2], gy2 = sbox[g][3];
            float a2 = fmaxf(gx2-gx1, 0.f) * fmaxf(gy2-gy1, 0.f);
            float ix1 = fmaxf(x1, gx1), iy1 = fmaxf(y1, gy1);
            float ix2 = fminf(x2, gx2), iy2 = fminf(y2, gy2);
            float iw = fmaxf(ix2-ix1, 0.f), ih = fmaxf(iy2-iy1, 0.f);
            float inter = iw*ih;
            float uni = a1 + a2 - inter;
            float iou = inter / fmaxf(uni, 1e-7f);
            best = fmaxf(best, iou);
        }
        // focal fixup at this scattered position
        int gidx = b*CHW_ + idx;
        float v = hm[gidx];
        float p = 1.f/(1.f + __expf(-v));
        p = fminf(fmaxf(p, 1e-4f), 1.f - 1e-4f);
        float gt0 = hmt[gidx];
        float q0 = 1.f - gt0; float q02 = q0*q0;
        float neg0 = __logf(1.f - p) * p * p * q02 * q02;
        float gt1 = fminf(gt0 + 0.1f*best, 1.f);
        if(gt1 == 1.f){
            atomicAdd(&misc[0], 1);
            float op = 1.f - p;
            atomicAdd(&accum[1], (double)(__logf(p)*op*op));
            atomicAdd(&accum[2], (double)(-neg0));
        } else {
            float q1 = 1.f - gt1; float q12 = q1*q1;
            float neg1 = __logf(1.f - p) * p * p * q12 * q12;
            atomicAdd(&accum[2], (double)(neg1 - neg0));
        }
    }
}

// Tiny masked-L1 heads (wh / offset)
__global__ void k_reg(const float* __restrict__ wh, const float* __restrict__ reg,
                      const float* __restrict__ wht, const float* __restrict__ regt,
                      const int* __restrict__ mask, const int* __restrict__ ind,
                      double* __restrict__ accum){
    int tid = threadIdx.x;
    float whn = 0.f, offn = 0.f, ms = 0.f;
    for(int i=tid; i<B_*MAXOBJS_; i+=256){
        int b = i / MAXOBJS_;
        float mk = (float)mask[i];
        int id = ind[i];
        float p0 = wh[(b*2+0)*HW_ + id], p1 = wh[(b*2+1)*HW_ + id];
        whn += mk*(fabsf(p0 - wht[2*i]) + fabsf(p1 - wht[2*i+1]));
        float q0 = reg[(b*2+0)*HW_ + id], q1 = reg[(b*2+1)*HW_ + id];
        offn += mk*(fabsf(q0 - regt[2*i]) + fabsf(q1 - regt[2*i+1]));
        ms += 2.f*mk;
    }
    __shared__ float r0[256], r1[256], r2[256];
    r0[tid] = whn; r1[tid] = offn; r2[tid] = ms;
    __syncthreads();
    for(int st=128; st>0; st>>=1){
        if(tid < st){ r0[tid]+=r0[tid+st]; r1[tid]+=r1[tid+st]; r2[tid]+=r2[tid+st]; }
        __syncthreads();
    }
    if(tid == 0){ accum[3] = (double)r0[0]; accum[4] = (double)r1[0]; accum[5] = (double)r2[0]; }
}

__global__ void k_final(const double* __restrict__ accum, const int* __restrict__ misc,
                        float* __restrict__ out){
    if(threadIdx.x == 0 && blockIdx.x == 0){
        double neg = accum[0] + accum[2];
        double pos = accum[1];
        int np = misc[0];
        float hm_loss;
        if(np > 0) hm_loss = (float)(-(pos + neg) / (double)(np < 1 ? 1 : np));
        else       hm_loss = (float)(-neg);
        float msum = (float)accum[5];
        float wh_loss  = (float)accum[3] / (msum + 1e-4f);
        float off_loss = (float)accum[4] / (msum + 1e-4f);
        float loss = hm_loss + 0.1f*wh_loss + off_loss;
        out[0] = loss; out[1] = hm_loss; out[2] = wh_loss; out[3] = off_loss;
    }
}

extern "C" void kernel_launch(void* const* d_in, const int* in_sizes, int n_in,
                              void* d_out, int out_size, void* d_ws, size_t ws_size,
                              hipStream_t stream){
    const float* hm   = (const float*)d_in[0];
    const float* wh   = (const float*)d_in[1];
    const float* reg  = (const float*)d_in[2];
    const float* hmt  = (const float*)d_in[3];
    const float* wht  = (const float*)d_in[4];
    const float* regt = (const float*)d_in[5];
    const int*   mask = (const int*)d_in[6];
    const int*   ind  = (const int*)d_in[7];
    const float* tbox = (const float*)d_in[8];
    const int*   tbid = (const int*)d_in[9];

    char* ws = (char*)d_ws;
    double*   accum  = (double*)ws;
    int*      misc   = (int*)(ws + 64);
    unsigned* hist   = (unsigned*)(ws + 128);
    unsigned* thrbin = (unsigned*)(ws + OFF_THR);
    unsigned* cntab  = (unsigned*)(ws + OFF_CNTAB);
    unsigned* cntA   = (unsigned*)(ws + OFF_CNTA);
    unsigned* cntB   = (unsigned*)(ws + OFF_CNTB);
    float*    defv   = (float*)(ws + OFF_DEFV);
    int*      defi   = (int*)(ws + OFF_DEFI);
    float*    borv   = (float*)(ws + OFF_BORV);
    int*      bori   = (int*)(ws + OFF_BORI);

    hipMemsetAsync(ws, 0, ZERO_BYTES, stream);
    k_main<<<TOT_/256, 256, 0, stream>>>(hm, hmt, hist, accum);
    k_thresh<<<B_, 256, 0, stream>>>(hist, thrbin, cntab);
    k_collect<<<TOT_/256, 256, 0, stream>>>(hm, thrbin, cntA, cntB, defv, defi, borv, bori);
    k_batch<<<B_, 256, 0, stream>>>(hm, hmt, wh, reg, tbox, tbid, cntA, cntB,
                                    defv, defi, borv, bori, accum, misc);
    k_reg<<<1, 256, 0, stream>>>(wh, reg, wht, regt, mask, ind, accum);
    k_final<<<1, 64, 0, stream>>>(accum, misc, (float*)d_out);
    (void)in_sizes; (void)n_in; (void)out_size; (void)ws_size;
}

// Round 2
// 296.364 us; speedup vs baseline: 4.3659x; 4.3659x over previous
//
#include <hip/hip_runtime.h>
#include <math.h>

#define B_ 8
#define C_ 80
#define H_ 128
#define W_ 128
#define K_ 100
#define MAXOBJS_ 128
#define NGT_ 256
#define HW_ (H_*W_)
#define CHW_ (C_*H_*W_)
#define TOT_ (B_*CHW_)
#define NBINS_ 4096
#define BCAP_ 4096
#define DCAP_ 128
#define NBLKPB_ 256
#define CHUNK_ (CHW_/NBLKPB_)   // 5120
#define ITER_ (CHUNK_/256)      // 20

// ---- ws layout (bytes) ----
#define OFF_THR    131200
#define OFF_CNTAB  131232
#define OFF_CNTA   131264
#define OFF_CNTB   131296
#define OFF_DEFV   131328
#define OFF_DEFI   135424
#define OFF_BORV   139520
#define OFF_BORI   270592
#define ZERO_BYTES 131328

__device__ __forceinline__ unsigned skey(float x){
    unsigned u = __float_as_uint(x);
    return (u & 0x80000000u) ? ~u : (u | 0x80000000u);
}

__device__ __forceinline__ bool is_peak(const float* __restrict__ hm, int idx, float v){
    int w = idx & (W_-1);
    int h = (idx >> 7) & (H_-1);
    bool peak = true;
    #pragma unroll
    for(int dy=-1; dy<=1; ++dy){
        int hh = h + dy;
        if(hh < 0 || hh >= H_) continue;
        #pragma unroll
        for(int dx=-1; dx<=1; ++dx){
            if(dy==0 && dx==0) continue;
            int ww = w + dx;
            if(ww < 0 || ww >= W_) continue;
            peak = peak && (v >= __ldg(&hm[idx + dy*W_ + dx]));
        }
    }
    return peak;
}

// Pass 1: peak histogram (block-local LDS hist -> one global atomic per nonzero bin)
// + focal-loss negative base (gt = hm_target, no iou)
__global__ __launch_bounds__(256) void k_main(const float* __restrict__ hm,
                                              const float* __restrict__ hmt,
                                              unsigned* __restrict__ hist,
                                              double* __restrict__ accum){
    __shared__ unsigned lh[NBINS_];
    __shared__ float red[256];
    int tid = threadIdx.x;
    int b   = blockIdx.x >> 8;          // 256 blocks per batch
    int blk = blockIdx.x & 255;
    int base = b*CHW_ + blk*CHUNK_;

    for(int i=tid; i<NBINS_; i+=256) lh[i] = 0u;
    __syncthreads();

    float acc = 0.f;
    #pragma unroll 4
    for(int it=0; it<ITER_; ++it){
        int idx = base + it*256 + tid;
        float v = hm[idx];
        if(is_peak(hm, idx, v)){
            atomicAdd(&lh[skey(v)>>20], 1u);
        }
        float p = 1.f/(1.f + __expf(-v));
        p = fminf(fmaxf(p, 1e-4f), 1.f - 1e-4f);
        float gt = hmt[idx];
        float q = 1.f - gt;
        float q2 = q*q;
        acc += __logf(1.f - p) * p * p * q2 * q2;
    }
    __syncthreads();

    // flush LDS hist: one global atomic per nonzero bin (max 256 same-addr/bin)
    for(int i=tid; i<NBINS_; i+=256){
        unsigned c = lh[i];
        if(c) atomicAdd(&hist[b*NBINS_ + i], c);
    }

    red[tid] = acc;
    __syncthreads();
    for(int s=128; s>0; s>>=1){
        if(tid < s) red[tid] += red[tid+s];
        __syncthreads();
    }
    if(tid == 0) atomicAdd(&accum[0], (double)red[0]);
}

// Find per-batch threshold bin: smallest set of top bins with cum count >= K
__global__ void k_thresh(const unsigned* __restrict__ hist,
                         unsigned* __restrict__ thrbin, unsigned* __restrict__ cntab){
    __shared__ unsigned lh[NBINS_];
    int b = blockIdx.x;
    for(int i=threadIdx.x; i<NBINS_; i+=blockDim.x) lh[i] = hist[b*NBINS_+i];
    __syncthreads();
    if(threadIdx.x == 0){
        unsigned cum = 0, thr = 0;
        for(int bin=NBINS_-1; bin>=0; --bin){
            unsigned c = lh[bin];
            if(cum + c >= K_){ thr = (unsigned)bin; break; }
            cum += c;
        }
        thrbin[b] = thr;
        cntab[b]  = cum;
    }
}

// Pass 2: collect definite (> thr bin) and borderline (== thr bin) peak candidates
__global__ __launch_bounds__(256) void k_collect(const float* __restrict__ hm,
                                                 const unsigned* __restrict__ thrbin,
                                                 unsigned* __restrict__ cntA, unsigned* __restrict__ cntB,
                                                 float* __restrict__ defv, int* __restrict__ defi,
                                                 float* __restrict__ borv, int* __restrict__ bori){
    int idx = blockIdx.x*256 + threadIdx.x;
    float v = hm[idx];
    if(!is_peak(hm, idx, v)) return;
    int b = idx / CHW_;
    unsigned bin = skey(v) >> 20;
    unsigned thr = thrbin[b];
    if(bin > thr){
        unsigned p = atomicAdd(&cntA[b], 1u);
        if(p < DCAP_){ defv[b*DCAP_+p] = v; defi[b*DCAP_+p] = idx - b*CHW_; }
    } else if(bin == thr){
        unsigned p = atomicAdd(&cntB[b], 1u);
        if(p < BCAP_){ borv[b*BCAP_+p] = v; bori[b*BCAP_+p] = idx - b*CHW_; }
    }
}

// Per-batch: finalize top-K set, decode boxes, IoU vs GT, focal fixup at scattered points
__global__ __launch_bounds__(256) void k_batch(const float* __restrict__ hm,
                                               const float* __restrict__ hmt,
                                               const float* __restrict__ wh,
                                               const float* __restrict__ reg,
                                               const float* __restrict__ tbox,
                                               const int* __restrict__ tbid,
                                               const unsigned* __restrict__ cntA,
                                               const unsigned* __restrict__ cntB,
                                               const float* __restrict__ defv, const int* __restrict__ defi,
                                               const float* __restrict__ borv, const int* __restrict__ bori,
                                               double* __restrict__ accum, int* __restrict__ misc){
    int b = blockIdx.x;
    int tid = threadIdx.x;
    __shared__ float sbox[NGT_][4];
    __shared__ int   sbid[NGT_];
    __shared__ float sv[BCAP_];
    __shared__ int   si[BCAP_];
    __shared__ float rv[256];
    __shared__ int   ri[256];
    __shared__ int   sel[K_];

    unsigned nAu = cntA[b];
    int nA = (nAu > (unsigned)DCAP_) ? DCAP_ : (int)nAu;
    if(nA > K_) nA = K_;
    unsigned nBu = cntB[b];
    int nB = (nBu > (unsigned)BCAP_) ? BCAP_ : (int)nBu;
    int m = K_ - nA;
    if(m > nB) m = nB;
    if(m < 0)  m = 0;

    for(int i=tid; i<nB; i+=256){ sv[i] = borv[b*BCAP_+i]; si[i] = bori[b*BCAP_+i]; }
    for(int i=tid; i<NGT_; i+=256){
        sbox[i][0] = tbox[i*4+0]; sbox[i][1] = tbox[i*4+1];
        sbox[i][2] = tbox[i*4+2]; sbox[i][3] = tbox[i*4+3];
        sbid[i] = tbid[i];
    }
    __syncthreads();

    for(int it=0; it<m; ++it){
        float bv = -INFINITY; int bi = -1;
        for(int i=tid; i<nB; i+=256){
            if(sv[i] > bv){ bv = sv[i]; bi = i; }
        }
        rv[tid] = bv; ri[tid] = bi;
        __syncthreads();
        for(int st=128; st>0; st>>=1){
            if(tid < st){
                if(rv[tid+st] > rv[tid]){ rv[tid] = rv[tid+st]; ri[tid] = ri[tid+st]; }
            }
            __syncthreads();
        }
        if(tid == 0){ sel[it] = si[ri[0]]; sv[ri[0]] = -INFINITY; }
        __syncthreads();
    }
    for(int i=tid; i<nA; i+=256) sel[m+i] = defi[b*DCAP_+i];
    __syncthreads();

    int nsel = m + nA;
    for(int k=tid; k<nsel; k+=256){
        int idx = sel[k];
        int cls = idx / HW_;
        int sp  = idx - cls*HW_;
        int yi  = sp >> 7;
        int xi  = sp & (W_-1);
        float r0 = reg[(b*2+0)*HW_ + sp];
        float r1 = reg[(b*2+1)*HW_ + sp];
        float w0 = wh[(b*2+0)*HW_ + sp];
        float w1 = wh[(b*2+1)*HW_ + sp];
        float xs = (float)xi + r0;
        float ys = (float)yi + r1;
        float x1 = xs - w0*0.5f, y1 = ys - w1*0.5f;
        float x2 = xs + w0*0.5f, y2 = ys + w1*0.5f;
        float a1 = fmaxf(x2-x1, 0.f) * fmaxf(y2-y1, 0.f);
        float best = 0.f;
        for(int g=0; g<NGT_; ++g){
            if(sbid[g] != b) continue;
            float gx1 = sbox[g][0], gy1 = sbox[g][1], gx2 = sbox[g][2], gy2 = sbox[g][3];
            float a2 = fmaxf(gx2-gx1, 0.f) * fmaxf(gy2-gy1, 0.f);
            float ix1 = fmaxf(x1, gx1), iy1 = fmaxf(y1, gy1);
            float ix2 = fminf(x2, gx2), iy2 = fminf(y2, gy2);
            float iw = fmaxf(ix2-ix1, 0.f), ih = fmaxf(iy2-iy1, 0.f);
            float inter = iw*ih;
            float uni = a1 + a2 - inter;
            float iou = inter / fmaxf(uni, 1e-7f);
            best = fmaxf(best, iou);
        }
        int gidx = b*CHW_ + idx;
        float v = hm[gidx];
        float p = 1.f/(1.f + __expf(-v));
        p = fminf(fmaxf(p, 1e-4f), 1.f - 1e-4f);
        float gt0 = hmt[gidx];
        float q0 = 1.f - gt0; float q02 = q0*q0;
        float neg0 = __logf(1.f - p) * p * p * q02 * q02;
        float gt1 = fminf(gt0 + 0.1f*best, 1.f);
        if(gt1 == 1.f){
            atomicAdd(&misc[0], 1);
            float op = 1.f - p;
            atomicAdd(&accum[1], (double)(__logf(p)*op*op));
            atomicAdd(&accum[2], (double)(-neg0));
        } else {
            float q1 = 1.f - gt1; float q12 = q1*q1;
            float neg1 = __logf(1.f - p) * p * p * q12 * q12;
            atomicAdd(&accum[2], (double)(neg1 - neg0));
        }
    }
}

// Tiny masked-L1 heads (wh / offset)
__global__ void k_reg(const float* __restrict__ wh, const float* __restrict__ reg,
                      const float* __restrict__ wht, const float* __restrict__ regt,
                      const int* __restrict__ mask, const int* __restrict__ ind,
                      double* __restrict__ accum){
    int tid = threadIdx.x;
    float whn = 0.f, offn = 0.f, ms = 0.f;
    for(int i=tid; i<B_*MAXOBJS_; i+=256){
        int b = i / MAXOBJS_;
        float mk = (float)mask[i];
        int id = ind[i];
        float p0 = wh[(b*2+0)*HW_ + id], p1 = wh[(b*2+1)*HW_ + id];
        whn += mk*(fabsf(p0 - wht[2*i]) + fabsf(p1 - wht[2*i+1]));
        float q0 = reg[(b*2+0)*HW_ + id], q1 = reg[(b*2+1)*HW_ + id];
        offn += mk*(fabsf(q0 - regt[2*i]) + fabsf(q1 - regt[2*i+1]));
        ms += 2.f*mk;
    }
    __shared__ float r0[256], r1[256], r2[256];
    r0[tid] = whn; r1[tid] = offn; r2[tid] = ms;
    __syncthreads();
    for(int st=128; st>0; st>>=1){
        if(tid < st){ r0[tid]+=r0[tid+st]; r1[tid]+=r1[tid+st]; r2[tid]+=r2[tid+st]; }
        __syncthreads();
    }
    if(tid == 0){ accum[3] = (double)r0[0]; accum[4] = (double)r1[0]; accum[5] = (double)r2[0]; }
}

__global__ void k_final(const double* __restrict__ accum, const int* __restrict__ misc,
                        float* __restrict__ out){
    if(threadIdx.x == 0 && blockIdx.x == 0){
        double neg = accum[0] + accum[2];
        double pos = accum[1];
        int np = misc[0];
        float hm_loss;
        if(np > 0) hm_loss = (float)(-(pos + neg) / (double)(np < 1 ? 1 : np));
        else       hm_loss = (float)(-neg);
        float msum = (float)accum[5];
        float wh_loss  = (float)accum[3] / (msum + 1e-4f);
        float off_loss = (float)accum[4] / (msum + 1e-4f);
        float loss = hm_loss + 0.1f*wh_loss + off_loss;
        out[0] = loss; out[1] = hm_loss; out[2] = wh_loss; out[3] = off_loss;
    }
}

extern "C" void kernel_launch(void* const* d_in, const int* in_sizes, int n_in,
                              void* d_out, int out_size, void* d_ws, size_t ws_size,
                              hipStream_t stream){
    const float* hm   = (const float*)d_in[0];
    const float* wh   = (const float*)d_in[1];
    const float* reg  = (const float*)d_in[2];
    const float* hmt  = (const float*)d_in[3];
    const float* wht  = (const float*)d_in[4];
    const float* regt = (const float*)d_in[5];
    const int*   mask = (const int*)d_in[6];
    const int*   ind  = (const int*)d_in[7];
    const float* tbox = (const float*)d_in[8];
    const int*   tbid = (const int*)d_in[9];

    char* ws = (char*)d_ws;
    double*   accum  = (double*)ws;
    int*      misc   = (int*)(ws + 64);
    unsigned* hist   = (unsigned*)(ws + 128);
    unsigned* thrbin = (unsigned*)(ws + OFF_THR);
    unsigned* cntab  = (unsigned*)(ws + OFF_CNTAB);
    unsigned* cntA   = (unsigned*)(ws + OFF_CNTA);
    unsigned* cntB   = (unsigned*)(ws + OFF_CNTB);
    float*    defv   = (float*)(ws + OFF_DEFV);
    int*      defi   = (int*)(ws + OFF_DEFI);
    float*    borv   = (float*)(ws + OFF_BORV);
    int*      bori   = (int*)(ws + OFF_BORI);

    hipMemsetAsync(ws, 0, ZERO_BYTES, stream);
    k_main<<<B_*NBLKPB_, 256, 0, stream>>>(hm, hmt, hist, accum);
    k_thresh<<<B_, 256, 0, stream>>>(hist, thrbin, cntab);
    k_collect<<<TOT_/256, 256, 0, stream>>>(hm, thrbin, cntA, cntB, defv, defi, borv, bori);
    k_batch<<<B_, 256, 0, stream>>>(hm, hmt, wh, reg, tbox, tbid, cntA, cntB,
                                    defv, defi, borv, bori, accum, misc);
    k_reg<<<1, 256, 0, stream>>>(wh, reg, wht, regt, mask, ind, accum);
    k_final<<<1, 64, 0, stream>>>(accum, misc, (float*)d_out);
    (void)in_sizes; (void)n_in; (void)out_size; (void)ws_size;
}

// Round 3
// 124.639 us; speedup vs baseline: 10.3811x; 2.3778x over previous
//
#include <hip/hip_runtime.h>
#include <math.h>

#define B_ 8
#define C_ 80
#define H_ 128
#define W_ 128
#define K_ 100
#define MAXOBJS_ 128
#define NGT_ 256
#define HW_ (H_*W_)
#define CHW_ (C_*H_*W_)
#define TOT_ (B_*CHW_)
#define NBINS_ 4096
#define BCAP_ 4096
#define DCAP_ 128
#define CAPLDS_ 3072
#define NEGINF_ (-INFINITY)

// ---- ws layout (bytes) ----
// [0,64)   double accum[8]: 0 neg_base, 1 pos_sum, 2 neg_delta, 3 wh_num, 4 off_num, 5 mask_sum
// [64,96)  int misc[8]: 0 num_pos
// [96,128) u32 listcnt[8]   (inside zeroed prefix)
#define OFF_LISTCNT 96
#define OFF_HIST   128
#define OFF_THR    131200
#define OFF_CNTAB  131232
#define OFF_CNTA   131264
#define OFF_CNTB   131296
#define OFF_DEFV   131328
#define OFF_DEFI   135424
#define OFF_BORV   139520
#define OFF_BORI   270592
#define OFF_LIST   401664
#define ZERO_BYTES 131328
#define CAP_REQ    196608ull   // required per-batch list capacity for path A
#define CAP_MAX    262144ull

__device__ __forceinline__ unsigned skey(float x){
    unsigned u = __float_as_uint(x);
    return (u & 0x80000000u) ? ~u : (u | 0x80000000u);
}

struct Row { float v[4]; float le, re; };

__device__ __forceinline__ Row loadrow(const float* __restrict__ P, int y, int xq){
    Row r;
    if(y < 0 || y >= H_){
        r.v[0]=r.v[1]=r.v[2]=r.v[3]=r.le=r.re=NEGINF_;
        return r;
    }
    const float4 f = *(const float4*)(P + y*W_ + xq*4);
    r.v[0]=f.x; r.v[1]=f.y; r.v[2]=f.z; r.v[3]=f.w;
    r.le = (xq==0) ? NEGINF_ : P[y*W_ + xq*4 - 1];
    r.re = (xq==31)? NEGINF_ : P[y*W_ + xq*4 + 4];
    return r;
}

__device__ __forceinline__ void hmax4(const Row& r, float h[4]){
    h[0]=fmaxf(fmaxf(r.le,  r.v[0]), r.v[1]);
    h[1]=fmaxf(fmaxf(r.v[0],r.v[1]), r.v[2]);
    h[2]=fmaxf(fmaxf(r.v[1],r.v[2]), r.v[3]);
    h[3]=fmaxf(fmaxf(r.v[2],r.v[3]), r.re);
}

// Pass 1 (one block per (b,c) plane): vectorized 3x3 peak stencil with register
// row-rolling, LDS histogram of peak keys, compact peak-list emission (path A),
// and the focal-loss negative base (gt = hm_target).
__global__ __launch_bounds__(256) void k_main(const float* __restrict__ hm,
        const float* __restrict__ hmt, unsigned* __restrict__ hist,
        double* __restrict__ accum, unsigned* __restrict__ listcnt,
        int2* __restrict__ list, int capB){
    __shared__ unsigned lh[NBINS_];
    __shared__ int2 lbuf[CAPLDS_];
    __shared__ unsigned lcnt, lbase;
    __shared__ float red[256];
    int t = threadIdx.x;
    int plane = blockIdx.x;
    int b = plane / C_;
    int cls = plane - b*C_;
    const float* P = hm  + (size_t)plane*HW_;
    const float* T = hmt + (size_t)plane*HW_;
    int idx0 = cls*HW_;

    for(int i=t;i<NBINS_;i+=256) lh[i]=0u;
    if(t==0) lcnt=0u;
    __syncthreads();

    int xq = t & 31;
    int y0 = (t >> 5) * 16;
    Row rp = loadrow(P, y0-1, xq);
    Row rc = loadrow(P, y0,   xq);
    float hp[4], hc[4];
    hmax4(rp, hp); hmax4(rc, hc);
    float acc = 0.f;
    for(int rr=0; rr<16; ++rr){
        int y = y0 + rr;
        Row rn = loadrow(P, y+1, xq);
        float hn[4]; hmax4(rn, hn);
        float lr[4];
        lr[0]=fmaxf(rc.le,  rc.v[1]);
        lr[1]=fmaxf(rc.v[0],rc.v[2]);
        lr[2]=fmaxf(rc.v[1],rc.v[3]);
        lr[3]=fmaxf(rc.v[2],rc.re);
        float4 tg = *(const float4*)(T + y*W_ + xq*4);
        float tgv[4] = {tg.x, tg.y, tg.z, tg.w};
        #pragma unroll
        for(int j=0;j<4;++j){
            float v = rc.v[j];
            bool pk = (v>=lr[j]) && (v>=hp[j]) && (v>=hn[j]);
            if(pk){
                atomicAdd(&lh[skey(v)>>20], 1u);
                if(capB){
                    unsigned p = atomicAdd(&lcnt, 1u);
                    int2 e; e.x = __float_as_int(v); e.y = idx0 + y*W_ + xq*4 + j;
                    if(p < CAPLDS_) lbuf[p] = e;
                    else {
                        unsigned g = atomicAdd(&listcnt[b], 1u);
                        if(g < (unsigned)capB) list[(size_t)b*capB + g] = e;
                    }
                }
            }
            float pr = 1.f/(1.f + __expf(-v));
            pr = fminf(fmaxf(pr, 1e-4f), 1.f - 1e-4f);
            float q = 1.f - tgv[j]; float q2 = q*q;
            acc += __logf(1.f - pr) * pr * pr * q2 * q2;
        }
        rc = rn;
        #pragma unroll
        for(int j=0;j<4;++j){ hp[j]=hc[j]; hc[j]=hn[j]; }
    }
    __syncthreads();
    unsigned n = lcnt; if(n > CAPLDS_) n = CAPLDS_;
    if(capB && t==0) lbase = atomicAdd(&listcnt[b], n);
    for(int i=t;i<NBINS_;i+=256){ unsigned c=lh[i]; if(c) atomicAdd(&hist[b*NBINS_+i], c); }
    red[t] = acc;
    __syncthreads();
    if(capB){
        for(unsigned i=t;i<n;i+=256){
            unsigned g = lbase + i;
            if(g < (unsigned)capB) list[(size_t)b*capB + g] = lbuf[i];
        }
    }
    for(int s=128;s>0;s>>=1){
        if(t<s) red[t]+=red[t+s];
        __syncthreads();
    }
    if(t==0) atomicAdd(&accum[0], (double)red[0]);
}

// Per-batch threshold bin (parallel partial sums, then short serial walk)
__global__ void k_thresh(const unsigned* __restrict__ hist,
                         unsigned* __restrict__ thrbin, unsigned* __restrict__ cntab){
    __shared__ unsigned lh[NBINS_];
    __shared__ unsigned part[256];
    int b = blockIdx.x, t = threadIdx.x;
    for(int i=t;i<NBINS_;i+=256) lh[i]=hist[b*NBINS_+i];
    __syncthreads();
    unsigned s=0;
    for(int k=0;k<16;++k) s += lh[t*16+k];
    part[t]=s;
    __syncthreads();
    if(t==0){
        unsigned cum=0; int cc=255;
        for(;cc>0;--cc){ if(cum+part[cc] >= (unsigned)K_) break; cum+=part[cc]; }
        int thr=cc*16;
        for(int bin=cc*16+15; bin>=cc*16; --bin){
            unsigned c=lh[bin];
            if(cum+c >= (unsigned)K_){ thr=bin; break; }
            cum+=c;
        }
        thrbin[b]=(unsigned)thr; cntab[b]=cum;
    }
}

// Path A: classify the compact peak lists vs the threshold bin
__global__ __launch_bounds__(256) void k_scan(const int2* __restrict__ list,
        const unsigned* __restrict__ listcnt, int capB,
        const unsigned* __restrict__ thrbin,
        unsigned* __restrict__ cntA, unsigned* __restrict__ cntB,
        float* __restrict__ defv, int* __restrict__ defi,
        float* __restrict__ borv, int* __restrict__ bori){
    int b = blockIdx.x >> 6;
    int chunk = blockIdx.x & 63;
    unsigned n = listcnt[b]; if(n > (unsigned)capB) n = (unsigned)capB;
    unsigned thr = thrbin[b];
    for(unsigned i = chunk*256u + threadIdx.x; i < n; i += 64u*256u){
        int2 e = list[(size_t)b*capB + i];
        float v = __int_as_float(e.x);
        unsigned bin = skey(v) >> 20;
        if(bin > thr){
            unsigned p = atomicAdd(&cntA[b], 1u);
            if(p < DCAP_){ defv[b*DCAP_+p]=v; defi[b*DCAP_+p]=e.y; }
        } else if(bin == thr){
            unsigned p = atomicAdd(&cntB[b], 1u);
            if(p < BCAP_){ borv[b*BCAP_+p]=v; bori[b*BCAP_+p]=e.y; }
        }
    }
}

// Path B fallback (small ws): full rescan of hm with scalar stencil
__device__ __forceinline__ bool is_peak_scalar(const float* __restrict__ hm, int idx, float v){
    int w = idx & (W_-1);
    int h = (idx >> 7) & (H_-1);
    bool peak = true;
    #pragma unroll
    for(int dy=-1; dy<=1; ++dy){
        int hh = h + dy;
        if(hh < 0 || hh >= H_) continue;
        #pragma unroll
        for(int dx=-1; dx<=1; ++dx){
            if(dy==0 && dx==0) continue;
            int ww = w + dx;
            if(ww < 0 || ww >= W_) continue;
            peak = peak && (v >= __ldg(&hm[idx + dy*W_ + dx]));
        }
    }
    return peak;
}

__global__ __launch_bounds__(256) void k_collect(const float* __restrict__ hm,
        const unsigned* __restrict__ thrbin,
        unsigned* __restrict__ cntA, unsigned* __restrict__ cntB,
        float* __restrict__ defv, int* __restrict__ defi,
        float* __restrict__ borv, int* __restrict__ bori){
    int idx = blockIdx.x*256 + threadIdx.x;
    float v = hm[idx];
    if(!is_peak_scalar(hm, idx, v)) return;
    int b = idx / CHW_;
    unsigned bin = skey(v) >> 20;
    unsigned thr = thrbin[b];
    if(bin > thr){
        unsigned p = atomicAdd(&cntA[b], 1u);
        if(p < DCAP_){ defv[b*DCAP_+p] = v; defi[b*DCAP_+p] = idx - b*CHW_; }
    } else if(bin == thr){
        unsigned p = atomicAdd(&cntB[b], 1u);
        if(p < BCAP_){ borv[b*BCAP_+p] = v; bori[b*BCAP_+p] = idx - b*CHW_; }
    }
}

// Per-batch: radix-refine the borderline bin to finalize the top-K set (no
// long argmax loops), then decode boxes, IoU vs GT, focal fixup.
__global__ __launch_bounds__(256) void k_select(const float* __restrict__ hm,
        const float* __restrict__ hmt, const float* __restrict__ wh,
        const float* __restrict__ reg, const float* __restrict__ tbox,
        const int* __restrict__ tbid,
        const unsigned* __restrict__ cntA, const unsigned* __restrict__ cntB,
        const float* __restrict__ defv, const int* __restrict__ defi,
        const float* __restrict__ borv, const int* __restrict__ bori,
        double* __restrict__ accum, int* __restrict__ misc){
    int b = blockIdx.x, t = threadIdx.x;
    __shared__ float sbox[NGT_][4];
    __shared__ int   sbid[NGT_];
    __shared__ float sv[BCAP_];
    __shared__ int   si[BCAP_];
    __shared__ unsigned h2[NBINS_];   // level-2 hist, later reused as exact-tie idx buffer
    __shared__ unsigned t4[BCAP_];    // tier-2 tie candidate indices (into sv/si)
    __shared__ unsigned part[256];
    __shared__ int  rvI[256];
    __shared__ int  sel[K_];
    __shared__ unsigned selc, t3c, t4c;
    __shared__ unsigned thr2s, need2s, thr3s, need3s;
    __shared__ int wsel;

    int nA = (int)cntA[b]; if(nA>DCAP_) nA=DCAP_; if(nA>K_) nA=K_;
    int nB = (int)cntB[b]; if(nB>BCAP_) nB=BCAP_;
    int m = K_ - nA; if(m>nB) m=nB; if(m<0) m=0;

    for(int i=t;i<NGT_;i+=256){
        sbox[i][0]=tbox[i*4+0]; sbox[i][1]=tbox[i*4+1];
        sbox[i][2]=tbox[i*4+2]; sbox[i][3]=tbox[i*4+3];
        sbid[i]=tbid[i];
    }
    for(int i=t;i<nB;i+=256){ sv[i]=borv[b*BCAP_+i]; si[i]=bori[b*BCAP_+i]; }
    for(int i=t;i<nA;i+=256) sel[i]=defi[b*DCAP_+i];
    if(t==0){ selc=(unsigned)nA; t3c=0u; t4c=0u; }
    for(int i=t;i<NBINS_;i+=256) h2[i]=0u;
    __syncthreads();

    if(m>0){
        // level 2: 12-bit sub-histogram on key bits [19:8]
        for(int i=t;i<nB;i+=256) atomicAdd(&h2[(skey(sv[i])>>8)&0xFFFu], 1u);
        __syncthreads();
        unsigned s=0;
        for(int k=0;k<16;++k) s += h2[t*16+k];
        part[t]=s;
        __syncthreads();
        if(t==0){
            unsigned cum=0; int cc=255;
            for(;cc>0;--cc){ if(cum+part[cc] >= (unsigned)m) break; cum+=part[cc]; }
            int thr=cc*16;
            for(int bin=cc*16+15; bin>=cc*16; --bin){
                unsigned c=h2[bin];
                if(cum+c >= (unsigned)m){ thr=bin; break; }
                cum+=c;
            }
            thr2s=(unsigned)thr; need2s=(unsigned)m-cum;
        }
        __syncthreads();
        unsigned thr2=thr2s, need2=need2s;
        for(int i=t;i<nB;i+=256){
            unsigned sb=(skey(sv[i])>>8)&0xFFFu;
            if(sb>thr2){ unsigned p=atomicAdd(&selc,1u); if(p<K_) sel[p]=si[i]; }
            else if(sb==thr2){ unsigned p=atomicAdd(&t3c,1u); if(p<BCAP_) t4[p]=(unsigned)i; }
        }
        __syncthreads();
        // level 3: 8-bit histogram on key bits [7:0] among tier-2 ties
        unsigned nt3=t3c; if(nt3>BCAP_) nt3=BCAP_;
        part[t]=0u;
        __syncthreads();
        for(unsigned i=t;i<nt3;i+=256) atomicAdd(&part[skey(sv[t4[i]])&0xFFu], 1u);
        __syncthreads();
        if(t==0){
            unsigned cum=0; int thr=0;
            for(int bin=255;bin>=0;--bin){
                unsigned c=part[bin];
                if(cum+c >= need2){ thr=bin; break; }
                cum+=c;
            }
            thr3s=(unsigned)thr; need3s=need2-cum;
        }
        __syncthreads();
        unsigned thr3=thr3s, need3=need3s;
        for(unsigned i=t;i<nt3;i+=256){
            unsigned ci=t4[i];
            unsigned lb=skey(sv[ci])&0xFFu;
            if(lb>thr3){ unsigned p=atomicAdd(&selc,1u); if(p<K_) sel[p]=si[ci]; }
            else if(lb==thr3){ unsigned p=atomicAdd(&t4c,1u); h2[p]=(unsigned)si[ci]; }
        }
        __syncthreads();
        // exact-value ties: take `need3` smallest spatial indices (jax tie-break)
        unsigned n4=t4c;
        if(need3 >= n4){
            for(unsigned i=t;i<n4;i+=256){ unsigned p=atomicAdd(&selc,1u); if(p<K_) sel[p]=(int)h2[i]; }
            __syncthreads();
        } else {
            for(unsigned it=0; it<need3; ++it){
                int bi=0x7FFFFFFF;
                for(unsigned i=t;i<n4;i+=256){ int w=(int)h2[i]; bi = (w<bi)?w:bi; }
                rvI[t]=bi;
                __syncthreads();
                for(int st=128;st>0;st>>=1){
                    if(t<st){ int w=rvI[t+st]; if(w<rvI[t]) rvI[t]=w; }
                    __syncthreads();
                }
                if(t==0){ wsel=rvI[0]; unsigned p=selc; selc=p+1u; if(p<K_) sel[p]=wsel; }
                __syncthreads();
                int w=wsel;
                for(unsigned i=t;i<n4;i+=256) if((int)h2[i]==w) h2[i]=0x7FFFFFFFu;
                __syncthreads();
            }
        }
    }
    __syncthreads();

    int nsel=(int)selc; if(nsel>K_) nsel=K_;
    for(int k=t;k<nsel;k+=256){
        int idx = sel[k];
        int cls = idx / HW_;
        int sp  = idx - cls*HW_;
        int yi  = sp >> 7;
        int xi  = sp & (W_-1);
        float r0 = reg[(b*2+0)*HW_ + sp];
        float r1 = reg[(b*2+1)*HW_ + sp];
        float w0 = wh[(b*2+0)*HW_ + sp];
        float w1 = wh[(b*2+1)*HW_ + sp];
        float xs = (float)xi + r0;
        float ys = (float)yi + r1;
        float x1 = xs - w0*0.5f, y1 = ys - w1*0.5f;
        float x2 = xs + w0*0.5f, y2 = ys + w1*0.5f;
        float a1 = fmaxf(x2-x1, 0.f) * fmaxf(y2-y1, 0.f);
        float best = 0.f;
        for(int g=0; g<NGT_; ++g){
            if(sbid[g] != b) continue;
            float gx1=sbox[g][0], gy1=sbox[g][1], gx2=sbox[g][2], gy2=sbox[g][3];
            float a2 = fmaxf(gx2-gx1, 0.f) * fmaxf(gy2-gy1, 0.f);
            float ix1 = fmaxf(x1,gx1), iy1 = fmaxf(y1,gy1);
            float ix2 = fminf(x2,gx2), iy2 = fminf(y2,gy2);
            float iw = fmaxf(ix2-ix1, 0.f), ih = fmaxf(iy2-iy1, 0.f);
            float inter = iw*ih;
            float uni = a1 + a2 - inter;
            float iou = inter / fmaxf(uni, 1e-7f);
            best = fmaxf(best, iou);
        }
        int gidx = b*CHW_ + idx;
        float v = hm[gidx];
        float p = 1.f/(1.f + __expf(-v));
        p = fminf(fmaxf(p, 1e-4f), 1.f - 1e-4f);
        float gt0 = hmt[gidx];
        float q0 = 1.f - gt0; float q02 = q0*q0;
        float neg0 = __logf(1.f - p) * p * p * q02 * q02;
        float gt1 = fminf(gt0 + 0.1f*best, 1.f);
        if(gt1 == 1.f){
            atomicAdd(&misc[0], 1);
            float op = 1.f - p;
            atomicAdd(&accum[1], (double)(__logf(p)*op*op));
            atomicAdd(&accum[2], (double)(-neg0));
        } else {
            float q1 = 1.f - gt1; float q12 = q1*q1;
            float neg1 = __logf(1.f - p) * p * p * q12 * q12;
            atomicAdd(&accum[2], (double)(neg1 - neg0));
        }
    }
}

// Masked-L1 heads + final combine (runs after k_select)
__global__ void k_regfinal(const float* __restrict__ wh, const float* __restrict__ reg,
        const float* __restrict__ wht, const float* __restrict__ regt,
        const int* __restrict__ mask, const int* __restrict__ ind,
        const double* __restrict__ accum, const int* __restrict__ misc,
        float* __restrict__ out){
    int tid = threadIdx.x;
    float whn = 0.f, offn = 0.f, ms = 0.f;
    for(int i=tid; i<B_*MAXOBJS_; i+=256){
        int b = i / MAXOBJS_;
        float mk = (float)mask[i];
        int id = ind[i];
        float p0 = wh[(b*2+0)*HW_ + id], p1 = wh[(b*2+1)*HW_ + id];
        whn += mk*(fabsf(p0 - wht[2*i]) + fabsf(p1 - wht[2*i+1]));
        float q0 = reg[(b*2+0)*HW_ + id], q1 = reg[(b*2+1)*HW_ + id];
        offn += mk*(fabsf(q0 - regt[2*i]) + fabsf(q1 - regt[2*i+1]));
        ms += 2.f*mk;
    }
    __shared__ float r0[256], r1[256], r2[256];
    r0[tid]=whn; r1[tid]=offn; r2[tid]=ms;
    __syncthreads();
    for(int st=128; st>0; st>>=1){
        if(tid<st){ r0[tid]+=r0[tid+st]; r1[tid]+=r1[tid+st]; r2[tid]+=r2[tid+st]; }
        __syncthreads();
    }
    if(tid==0){
        double neg = accum[0] + accum[2];
        double pos = accum[1];
        int np = misc[0];
        float hm_loss;
        if(np > 0) hm_loss = (float)(-(pos + neg) / (double)(np < 1 ? 1 : np));
        else       hm_loss = (float)(-neg);
        float msum = r2[0];
        float wh_loss  = r0[0] / (msum + 1e-4f);
        float off_loss = r1[0] / (msum + 1e-4f);
        float loss = hm_loss + 0.1f*wh_loss + off_loss;
        out[0]=loss; out[1]=hm_loss; out[2]=wh_loss; out[3]=off_loss;
    }
}

extern "C" void kernel_launch(void* const* d_in, const int* in_sizes, int n_in,
                              void* d_out, int out_size, void* d_ws, size_t ws_size,
                              hipStream_t stream){
    const float* hm   = (const float*)d_in[0];
    const float* wh   = (const float*)d_in[1];
    const float* reg  = (const float*)d_in[2];
    const float* hmt  = (const float*)d_in[3];
    const float* wht  = (const float*)d_in[4];
    const float* regt = (const float*)d_in[5];
    const int*   mask = (const int*)d_in[6];
    const int*   ind  = (const int*)d_in[7];
    const float* tbox = (const float*)d_in[8];
    const int*   tbid = (const int*)d_in[9];

    char* ws = (char*)d_ws;
    double*   accum   = (double*)ws;
    int*      misc    = (int*)(ws + 64);
    unsigned* listcnt = (unsigned*)(ws + OFF_LISTCNT);
    unsigned* hist    = (unsigned*)(ws + OFF_HIST);
    unsigned* thrbin  = (unsigned*)(ws + OFF_THR);
    unsigned* cntab   = (unsigned*)(ws + OFF_CNTAB);
    unsigned* cntA    = (unsigned*)(ws + OFF_CNTA);
    unsigned* cntB    = (unsigned*)(ws + OFF_CNTB);
    float*    defv    = (float*)(ws + OFF_DEFV);
    int*      defi    = (int*)(ws + OFF_DEFI);
    float*    borv    = (float*)(ws + OFF_BORV);
    int*      bori    = (int*)(ws + OFF_BORI);
    int2*     list    = (int2*)(ws + OFF_LIST);

    size_t capB = 0;
    if(ws_size >= (size_t)OFF_LIST + CAP_REQ*(size_t)B_*8ull){
        capB = (ws_size - (size_t)OFF_LIST) / ((size_t)B_*8ull);
        if(capB > CAP_MAX) capB = CAP_MAX;
    }

    hipMemsetAsync(ws, 0, ZERO_BYTES, stream);
    k_main<<<B_*C_, 256, 0, stream>>>(hm, hmt, hist, accum, listcnt, list, (int)capB);
    k_thresh<<<B_, 256, 0, stream>>>(hist, thrbin, cntab);
    if(capB)
        k_scan<<<B_*64, 256, 0, stream>>>(list, listcnt, (int)capB, thrbin,
                                          cntA, cntB, defv, defi, borv, bori);
    else
        k_collect<<<TOT_/256, 256, 0, stream>>>(hm, thrbin, cntA, cntB,
                                                defv, defi, borv, bori);
    k_select<<<B_, 256, 0, stream>>>(hm, hmt, wh, reg, tbox, tbid, cntA, cntB,
                                     defv, defi, borv, bori, accum, misc);
    k_regfinal<<<1, 256, 0, stream>>>(wh, reg, wht, regt, mask, ind, accum, misc,
                                      (float*)d_out);
    (void)in_sizes; (void)n_in; (void)out_size;
}

// Round 4
// 95.971 us; speedup vs baseline: 13.4822x; 1.2987x over previous
//
#include <hip/hip_runtime.h>
#include <math.h>

#define B_ 8
#define C_ 80
#define H_ 128
#define W_ 128
#define K_ 100
#define MAXOBJS_ 128
#define NGT_ 256
#define HW_ (H_*W_)
#define CHW_ (C_*H_*W_)
#define TOT_ (B_*CHW_)
#define NBINS_ 4096
#define BCAP_ 4096
#define DCAP_ 128
#define CAPLDS_ 3072
#define DLOC_ 128
#define BLOC_ 768
#define NEGINF_ (-INFINITY)

// ---- ws layout (bytes) ----
// [0,64)   double accum[8]: 0 neg_base, 1 pos_sum, 2 neg_delta
// [64,96)  int misc[8]: 0 num_pos
// [96,128) u32 listcnt[8]
#define OFF_LISTCNT 96
#define OFF_HIST   128
#define OFF_THR    131200
#define OFF_CNTA   131264
#define OFF_CNTB   131296
#define OFF_DEFV   131328
#define OFF_DEFI   135424
#define OFF_BORV   139520
#define OFF_BORI   270592
#define OFF_LIST   401664
#define ZERO_BYTES 131328
#define CAP_REQ    196608ull
#define CAP_MAX    262144ull

__device__ __forceinline__ unsigned skey(float x){
    unsigned u = __float_as_uint(x);
    return (u & 0x80000000u) ? ~u : (u | 0x80000000u);
}

// Parallel threshold-bin finder over a 4096-bin LDS hist.
// Finds largest bin with suffix-count >= target; *out_cum = count strictly above it.
// part[] is 256-u32 scratch. All 256 threads participate; syncs internally.
__device__ __forceinline__ void find_thr(const unsigned* __restrict__ lh,
                                         unsigned* __restrict__ part,
                                         unsigned target,
                                         unsigned* out_thr, unsigned* out_cum){
    int t = threadIdx.x;
    unsigned s = 0;
    #pragma unroll
    for(int k=0;k<16;++k) s += lh[t*16+k];
    part[t] = s;
    __syncthreads();
    for(int off=1; off<256; off<<=1){           // suffix scan: part[t] = sum_{u>=t}
        unsigned v = (t+off<256) ? part[t+off] : 0u;
        __syncthreads();
        part[t] += v;
        __syncthreads();
    }
    unsigned nxt = (t<255) ? part[t+1] : 0u;
    if(part[t] >= target && nxt < target){      // unique crossing slice
        unsigned cum = nxt;
        int thr = t*16;
        for(int bin=t*16+15; bin>=t*16; --bin){
            unsigned c = lh[bin];
            if(cum + c >= target){ thr = bin; break; }
            cum += c;
        }
        *out_thr = (unsigned)thr;
        *out_cum = cum;
    }
    __syncthreads();
}

struct Row { float v[4]; float le, re; };

__device__ __forceinline__ Row loadrow(const float* __restrict__ P, int y, int xq){
    Row r;
    if(y < 0 || y >= H_){
        r.v[0]=r.v[1]=r.v[2]=r.v[3]=r.le=r.re=NEGINF_;
        return r;
    }
    const float4 f = *(const float4*)(P + y*W_ + xq*4);
    r.v[0]=f.x; r.v[1]=f.y; r.v[2]=f.z; r.v[3]=f.w;
    r.le = (xq==0) ? NEGINF_ : P[y*W_ + xq*4 - 1];
    r.re = (xq==31)? NEGINF_ : P[y*W_ + xq*4 + 4];
    return r;
}

__device__ __forceinline__ void hmax4(const Row& r, float h[4]){
    h[0]=fmaxf(fmaxf(r.le,  r.v[0]), r.v[1]);
    h[1]=fmaxf(fmaxf(r.v[0],r.v[1]), r.v[2]);
    h[2]=fmaxf(fmaxf(r.v[1],r.v[2]), r.v[3]);
    h[3]=fmaxf(fmaxf(r.v[2],r.v[3]), r.re);
}

// Pass 1 (one block per (b,c) plane): vectorized 3x3 peak stencil, LDS key
// histogram, compact peak-list emission, focal-loss negative base.
__global__ __launch_bounds__(256) void k_main(const float* __restrict__ hm,
        const float* __restrict__ hmt, unsigned* __restrict__ hist,
        double* __restrict__ accum, unsigned* __restrict__ listcnt,
        int2* __restrict__ list, int capB){
    __shared__ unsigned lh[NBINS_];
    __shared__ int2 lbuf[CAPLDS_];
    __shared__ unsigned lcnt, lbase;
    __shared__ float red[256];
    int t = threadIdx.x;
    int plane = blockIdx.x;
    int b = plane / C_;
    int cls = plane - b*C_;
    const float* P = hm  + (size_t)plane*HW_;
    const float* T = hmt + (size_t)plane*HW_;
    int idx0 = cls*HW_;

    for(int i=t;i<NBINS_;i+=256) lh[i]=0u;
    if(t==0) lcnt=0u;
    __syncthreads();

    int xq = t & 31;
    int y0 = (t >> 5) * 16;
    Row rp = loadrow(P, y0-1, xq);
    Row rc = loadrow(P, y0,   xq);
    float hp[4], hc[4];
    hmax4(rp, hp); hmax4(rc, hc);
    float acc = 0.f;
    for(int rr=0; rr<16; ++rr){
        int y = y0 + rr;
        Row rn = loadrow(P, y+1, xq);
        float hn[4]; hmax4(rn, hn);
        float lr[4];
        lr[0]=fmaxf(rc.le,  rc.v[1]);
        lr[1]=fmaxf(rc.v[0],rc.v[2]);
        lr[2]=fmaxf(rc.v[1],rc.v[3]);
        lr[3]=fmaxf(rc.v[2],rc.re);
        float4 tg = *(const float4*)(T + y*W_ + xq*4);
        float tgv[4] = {tg.x, tg.y, tg.z, tg.w};
        #pragma unroll
        for(int j=0;j<4;++j){
            float v = rc.v[j];
            bool pk = (v>=lr[j]) && (v>=hp[j]) && (v>=hn[j]);
            if(pk){
                atomicAdd(&lh[skey(v)>>20], 1u);
                if(capB){
                    unsigned p = atomicAdd(&lcnt, 1u);
                    int2 e; e.x = __float_as_int(v); e.y = idx0 + y*W_ + xq*4 + j;
                    if(p < CAPLDS_) lbuf[p] = e;
                    else {
                        unsigned g = atomicAdd(&listcnt[b], 1u);
                        if(g < (unsigned)capB) list[(size_t)b*capB + g] = e;
                    }
                }
            }
            float pr = 1.f/(1.f + __expf(-v));
            pr = fminf(fmaxf(pr, 1e-4f), 1.f - 1e-4f);
            float q = 1.f - tgv[j]; float q2 = q*q;
            acc += __logf(1.f - pr) * pr * pr * q2 * q2;
        }
        rc = rn;
        #pragma unroll
        for(int j=0;j<4;++j){ hp[j]=hc[j]; hc[j]=hn[j]; }
    }
    __syncthreads();
    unsigned n = lcnt; if(n > CAPLDS_) n = CAPLDS_;
    if(capB && t==0) lbase = atomicAdd(&listcnt[b], n);
    for(int i=t;i<NBINS_;i+=256){ unsigned c=lh[i]; if(c) atomicAdd(&hist[b*NBINS_+i], c); }
    red[t] = acc;
    __syncthreads();
    if(capB){
        for(unsigned i=t;i<n;i+=256){
            unsigned g = lbase + i;
            if(g < (unsigned)capB) list[(size_t)b*capB + g] = lbuf[i];
        }
    }
    for(int s=128;s>0;s>>=1){
        if(t<s) red[t]+=red[t+s];
        __syncthreads();
    }
    if(t==0) atomicAdd(&accum[0], (double)red[0]);
}

// Path A: each block recomputes the threshold (parallel), classifies its chunk
// of the peak list with block-aggregated (ranged) global atomics.
__global__ __launch_bounds__(256) void k_scan(const int2* __restrict__ list,
        const unsigned* __restrict__ listcnt, int capB,
        const unsigned* __restrict__ hist,
        unsigned* __restrict__ cntA, unsigned* __restrict__ cntB,
        float* __restrict__ defv, int* __restrict__ defi,
        float* __restrict__ borv, int* __restrict__ bori){
    __shared__ unsigned lh[NBINS_];
    __shared__ unsigned part[256];
    __shared__ unsigned thrs, cums;
    __shared__ int2 dloc[DLOC_];
    __shared__ int2 bloc[BLOC_];
    __shared__ unsigned dc, bc, dbase, bbase;
    int b = blockIdx.x >> 6;
    int chunk = blockIdx.x & 63;
    int t = threadIdx.x;
    for(int i=t;i<NBINS_;i+=256) lh[i]=hist[b*NBINS_+i];
    if(t==0){ dc=0u; bc=0u; thrs=0u; cums=0u; }
    __syncthreads();
    find_thr(lh, part, (unsigned)K_, &thrs, &cums);
    unsigned thr = thrs;
    unsigned n = listcnt[b]; if(n > (unsigned)capB) n = (unsigned)capB;
    for(unsigned i = chunk*256u + t; i < n; i += 64u*256u){
        int2 e = list[(size_t)b*capB + i];
        float v = __int_as_float(e.x);
        unsigned bin = skey(v) >> 20;
        if(bin > thr){
            unsigned p = atomicAdd(&dc, 1u);
            if(p < DLOC_) dloc[p] = e;
            else { unsigned g = atomicAdd(&cntA[b],1u); if(g<DCAP_){ defv[b*DCAP_+g]=v; defi[b*DCAP_+g]=e.y; } }
        } else if(bin == thr){
            unsigned p = atomicAdd(&bc, 1u);
            if(p < BLOC_) bloc[p] = e;
            else { unsigned g = atomicAdd(&cntB[b],1u); if(g<BCAP_){ borv[b*BCAP_+g]=v; bori[b*BCAP_+g]=e.y; } }
        }
    }
    __syncthreads();
    unsigned dn = dc < DLOC_ ? dc : DLOC_;
    unsigned bn = bc < BLOC_ ? bc : BLOC_;
    if(t==0){
        dbase = dn ? atomicAdd(&cntA[b], dn) : 0u;
        bbase = bn ? atomicAdd(&cntB[b], bn) : 0u;
    }
    __syncthreads();
    for(unsigned i=t;i<dn;i+=256){
        unsigned g = dbase + i;
        if(g < DCAP_){ defv[b*DCAP_+g]=__int_as_float(dloc[i].x); defi[b*DCAP_+g]=dloc[i].y; }
    }
    for(unsigned i=t;i<bn;i+=256){
        unsigned g = bbase + i;
        if(g < BCAP_){ borv[b*BCAP_+g]=__int_as_float(bloc[i].x); bori[b*BCAP_+g]=bloc[i].y; }
    }
}

// Path B fallback (small ws): threshold kernel + full rescan
__global__ void k_thresh(const unsigned* __restrict__ hist, unsigned* __restrict__ thrbin){
    __shared__ unsigned lh[NBINS_];
    __shared__ unsigned part[256];
    __shared__ unsigned thrs, cums;
    int b = blockIdx.x, t = threadIdx.x;
    for(int i=t;i<NBINS_;i+=256) lh[i]=hist[b*NBINS_+i];
    if(t==0){ thrs=0u; cums=0u; }
    __syncthreads();
    find_thr(lh, part, (unsigned)K_, &thrs, &cums);
    if(t==0) thrbin[b]=thrs;
}

__device__ __forceinline__ bool is_peak_scalar(const float* __restrict__ hm, int idx, float v){
    int w = idx & (W_-1);
    int h = (idx >> 7) & (H_-1);
    bool peak = true;
    #pragma unroll
    for(int dy=-1; dy<=1; ++dy){
        int hh = h + dy;
        if(hh < 0 || hh >= H_) continue;
        #pragma unroll
        for(int dx=-1; dx<=1; ++dx){
            if(dy==0 && dx==0) continue;
            int ww = w + dx;
            if(ww < 0 || ww >= W_) continue;
            peak = peak && (v >= __ldg(&hm[idx + dy*W_ + dx]));
        }
    }
    return peak;
}

__global__ __launch_bounds__(256) void k_collect(const float* __restrict__ hm,
        const unsigned* __restrict__ thrbin,
        unsigned* __restrict__ cntA, unsigned* __restrict__ cntB,
        float* __restrict__ defv, int* __restrict__ defi,
        float* __restrict__ borv, int* __restrict__ bori){
    int idx = blockIdx.x*256 + threadIdx.x;
    float v = hm[idx];
    if(!is_peak_scalar(hm, idx, v)) return;
    int b = idx / CHW_;
    unsigned bin = skey(v) >> 20;
    unsigned thr = thrbin[b];
    if(bin > thr){
        unsigned p = atomicAdd(&cntA[b], 1u);
        if(p < DCAP_){ defv[b*DCAP_+p] = v; defi[b*DCAP_+p] = idx - b*CHW_; }
    } else if(bin == thr){
        unsigned p = atomicAdd(&cntB[b], 1u);
        if(p < BCAP_){ borv[b*BCAP_+p] = v; bori[b*BCAP_+p] = idx - b*CHW_; }
    }
}

// Per-batch: radix-refine borderline bin (all-parallel scans), decode boxes,
// IoU vs GT, focal fixup at scattered points.
__global__ __launch_bounds__(256) void k_select(const float* __restrict__ hm,
        const float* __restrict__ hmt, const float* __restrict__ wh,
        const float* __restrict__ reg, const float* __restrict__ tbox,
        const int* __restrict__ tbid,
        const unsigned* __restrict__ cntA, const unsigned* __restrict__ cntB,
        const float* __restrict__ defv, const int* __restrict__ defi,
        const float* __restrict__ borv, const int* __restrict__ bori,
        double* __restrict__ accum, int* __restrict__ misc){
    int b = blockIdx.x, t = threadIdx.x;
    __shared__ float sbox[NGT_][4];
    __shared__ int   sbid[NGT_];
    __shared__ float sv[BCAP_];
    __shared__ int   si[BCAP_];
    __shared__ unsigned h2[NBINS_];   // level-2 hist; reused as exact-tie buffer
    __shared__ unsigned t4[BCAP_];
    __shared__ unsigned part[256];
    __shared__ int  rvI[256];
    __shared__ int  sel[K_];
    __shared__ unsigned selc, t3c, t4c;
    __shared__ unsigned thr2s, cum2s, thr3s, need3s;
    __shared__ int wsel;

    int nA = (int)cntA[b]; if(nA>DCAP_) nA=DCAP_; if(nA>K_) nA=K_;
    int nB = (int)cntB[b]; if(nB>BCAP_) nB=BCAP_;
    int m = K_ - nA; if(m>nB) m=nB; if(m<0) m=0;

    for(int i=t;i<NGT_;i+=256){
        sbox[i][0]=tbox[i*4+0]; sbox[i][1]=tbox[i*4+1];
        sbox[i][2]=tbox[i*4+2]; sbox[i][3]=tbox[i*4+3];
        sbid[i]=tbid[i];
    }
    for(int i=t;i<nB;i+=256){ sv[i]=borv[b*BCAP_+i]; si[i]=bori[b*BCAP_+i]; }
    for(int i=t;i<nA;i+=256) sel[i]=defi[b*DCAP_+i];
    if(t==0){ selc=(unsigned)nA; t3c=0u; t4c=0u; thr2s=0u; cum2s=0u; thr3s=0u; need3s=0u; }
    for(int i=t;i<NBINS_;i+=256) h2[i]=0u;
    __syncthreads();

    if(m>0){
        // level 2: 12-bit hist on key bits [19:8], parallel threshold
        for(int i=t;i<nB;i+=256) atomicAdd(&h2[(skey(sv[i])>>8)&0xFFFu], 1u);
        __syncthreads();
        find_thr(h2, part, (unsigned)m, &thr2s, &cum2s);
        unsigned thr2 = thr2s, need2 = (unsigned)m - cum2s;
        for(int i=t;i<nB;i+=256){
            unsigned sb=(skey(sv[i])>>8)&0xFFFu;
            if(sb>thr2){ unsigned p=atomicAdd(&selc,1u); if(p<K_) sel[p]=si[i]; }
            else if(sb==thr2){ unsigned p=atomicAdd(&t3c,1u); if(p<BCAP_) t4[p]=(unsigned)i; }
        }
        __syncthreads();
        // level 3: 256-bin hist on key bits [7:0]; suffix-scan; no walk needed
        unsigned nt3=t3c; if(nt3>BCAP_) nt3=BCAP_;
        part[t]=0u;
        __syncthreads();
        for(unsigned i=t;i<nt3;i+=256) atomicAdd(&part[skey(sv[t4[i]])&0xFFu], 1u);
        __syncthreads();
        for(int off=1; off<256; off<<=1){
            unsigned v = (t+off<256)? part[t+off] : 0u;
            __syncthreads();
            part[t] += v;
            __syncthreads();
        }
        {
            unsigned nxt = (t<255)? part[t+1] : 0u;
            if(part[t] >= need2 && nxt < need2){ thr3s=(unsigned)t; need3s=need2-nxt; }
        }
        __syncthreads();
        unsigned thr3=thr3s, need3=need3s;
        for(unsigned i=t;i<nt3;i+=256){
            unsigned ci=t4[i];
            unsigned lb=skey(sv[ci])&0xFFu;
            if(lb>thr3){ unsigned p=atomicAdd(&selc,1u); if(p<K_) sel[p]=si[ci]; }
            else if(lb==thr3){ unsigned p=atomicAdd(&t4c,1u); if(p<NBINS_) h2[p]=(unsigned)si[ci]; }
        }
        __syncthreads();
        // exact-value ties: take `need3` smallest spatial indices (jax tie-break)
        unsigned n4=t4c; if(n4>NBINS_) n4=NBINS_;
        if(need3 >= n4){
            for(unsigned i=t;i<n4;i+=256){ unsigned p=atomicAdd(&selc,1u); if(p<K_) sel[p]=(int)h2[i]; }
            __syncthreads();
        } else {
            for(unsigned it=0; it<need3; ++it){
                int bi=0x7FFFFFFF;
                for(unsigned i=t;i<n4;i+=256){ int w=(int)h2[i]; bi = (w<bi)?w:bi; }
                rvI[t]=bi;
                __syncthreads();
                for(int st=128;st>0;st>>=1){
                    if(t<st){ int w=rvI[t+st]; if(w<rvI[t]) rvI[t]=w; }
                    __syncthreads();
                }
                if(t==0){ wsel=rvI[0]; unsigned p=selc; selc=p+1u; if(p<K_) sel[p]=wsel; }
                __syncthreads();
                int w=wsel;
                for(unsigned i=t;i<n4;i+=256) if((int)h2[i]==w) h2[i]=0x7FFFFFFFu;
                __syncthreads();
            }
        }
    }
    __syncthreads();

    int nsel=(int)selc; if(nsel>K_) nsel=K_;
    for(int k=t;k<nsel;k+=256){
        int idx = sel[k];
        int cls = idx / HW_;
        int sp  = idx - cls*HW_;
        int yi  = sp >> 7;
        int xi  = sp & (W_-1);
        float r0 = reg[(b*2+0)*HW_ + sp];
        float r1 = reg[(b*2+1)*HW_ + sp];
        float w0 = wh[(b*2+0)*HW_ + sp];
        float w1 = wh[(b*2+1)*HW_ + sp];
        float xs = (float)xi + r0;
        float ys = (float)yi + r1;
        float x1 = xs - w0*0.5f, y1 = ys - w1*0.5f;
        float x2 = xs + w0*0.5f, y2 = ys + w1*0.5f;
        float a1 = fmaxf(x2-x1, 0.f) * fmaxf(y2-y1, 0.f);
        float best = 0.f;
        for(int g=0; g<NGT_; ++g){
            if(sbid[g] != b) continue;
            float gx1=sbox[g][0], gy1=sbox[g][1], gx2=sbox[g][2], gy2=sbox[g][3];
            float a2 = fmaxf(gx2-gx1, 0.f) * fmaxf(gy2-gy1, 0.f);
            float ix1 = fmaxf(x1,gx1), iy1 = fmaxf(y1,gy1);
            float ix2 = fminf(x2,gx2), iy2 = fminf(y2,gy2);
            float iw = fmaxf(ix2-ix1, 0.f), ih = fmaxf(iy2-iy1, 0.f);
            float inter = iw*ih;
            float uni = a1 + a2 - inter;
            float iou = inter / fmaxf(uni, 1e-7f);
            best = fmaxf(best, iou);
        }
        int gidx = b*CHW_ + idx;
        float v = hm[gidx];
        float p = 1.f/(1.f + __expf(-v));
        p = fminf(fmaxf(p, 1e-4f), 1.f - 1e-4f);
        float gt0 = hmt[gidx];
        float q0 = 1.f - gt0; float q02 = q0*q0;
        float neg0 = __logf(1.f - p) * p * p * q02 * q02;
        float gt1 = fminf(gt0 + 0.1f*best, 1.f);
        if(gt1 == 1.f){
            atomicAdd(&misc[0], 1);
            float op = 1.f - p;
            atomicAdd(&accum[1], (double)(__logf(p)*op*op));
            atomicAdd(&accum[2], (double)(-neg0));
        } else {
            float q1 = 1.f - gt1; float q12 = q1*q1;
            float neg1 = __logf(1.f - p) * p * p * q12 * q12;
            atomicAdd(&accum[2], (double)(neg1 - neg0));
        }
    }
}

// Masked-L1 heads + final combine
__global__ void k_regfinal(const float* __restrict__ wh, const float* __restrict__ reg,
        const float* __restrict__ wht, const float* __restrict__ regt,
        const int* __restrict__ mask, const int* __restrict__ ind,
        const double* __restrict__ accum, const int* __restrict__ misc,
        float* __restrict__ out){
    int tid = threadIdx.x;
    float whn = 0.f, offn = 0.f, ms = 0.f;
    for(int i=tid; i<B_*MAXOBJS_; i+=256){
        int b = i / MAXOBJS_;
        float mk = (float)mask[i];
        int id = ind[i];
        float p0 = wh[(b*2+0)*HW_ + id], p1 = wh[(b*2+1)*HW_ + id];
        whn += mk*(fabsf(p0 - wht[2*i]) + fabsf(p1 - wht[2*i+1]));
        float q0 = reg[(b*2+0)*HW_ + id], q1 = reg[(b*2+1)*HW_ + id];
        offn += mk*(fabsf(q0 - regt[2*i]) + fabsf(q1 - regt[2*i+1]));
        ms += 2.f*mk;
    }
    __shared__ float r0[256], r1[256], r2[256];
    r0[tid]=whn; r1[tid]=offn; r2[tid]=ms;
    __syncthreads();
    for(int st=128; st>0; st>>=1){
        if(tid<st){ r0[tid]+=r0[tid+st]; r1[tid]+=r1[tid+st]; r2[tid]+=r2[tid+st]; }
        __syncthreads();
    }
    if(tid==0){
        double neg = accum[0] + accum[2];
        double pos = accum[1];
        int np = misc[0];
        float hm_loss;
        if(np > 0) hm_loss = (float)(-(pos + neg) / (double)(np < 1 ? 1 : np));
        else       hm_loss = (float)(-neg);
        float msum = r2[0];
        float wh_loss  = r0[0] / (msum + 1e-4f);
        float off_loss = r1[0] / (msum + 1e-4f);
        float loss = hm_loss + 0.1f*wh_loss + off_loss;
        out[0]=loss; out[1]=hm_loss; out[2]=wh_loss; out[3]=off_loss;
    }
}

extern "C" void kernel_launch(void* const* d_in, const int* in_sizes, int n_in,
                              void* d_out, int out_size, void* d_ws, size_t ws_size,
                              hipStream_t stream){
    const float* hm   = (const float*)d_in[0];
    const float* wh   = (const float*)d_in[1];
    const float* reg  = (const float*)d_in[2];
    const float* hmt  = (const float*)d_in[3];
    const float* wht  = (const float*)d_in[4];
    const float* regt = (const float*)d_in[5];
    const int*   mask = (const int*)d_in[6];
    const int*   ind  = (const int*)d_in[7];
    const float* tbox = (const float*)d_in[8];
    const int*   tbid = (const int*)d_in[9];

    char* ws = (char*)d_ws;
    double*   accum   = (double*)ws;
    int*      misc    = (int*)(ws + 64);
    unsigned* listcnt = (unsigned*)(ws + OFF_LISTCNT);
    unsigned* hist    = (unsigned*)(ws + OFF_HIST);
    unsigned* thrbin  = (unsigned*)(ws + OFF_THR);
    unsigned* cntA    = (unsigned*)(ws + OFF_CNTA);
    unsigned* cntB    = (unsigned*)(ws + OFF_CNTB);
    float*    defv    = (float*)(ws + OFF_DEFV);
    int*      defi    = (int*)(ws + OFF_DEFI);
    float*    borv    = (float*)(ws + OFF_BORV);
    int*      bori    = (int*)(ws + OFF_BORI);
    int2*     list    = (int2*)(ws + OFF_LIST);

    size_t capB = 0;
    if(ws_size >= (size_t)OFF_LIST + CAP_REQ*(size_t)B_*8ull){
        capB = (ws_size - (size_t)OFF_LIST) / ((size_t)B_*8ull);
        if(capB > CAP_MAX) capB = CAP_MAX;
    }

    hipMemsetAsync(ws, 0, ZERO_BYTES, stream);
    k_main<<<B_*C_, 256, 0, stream>>>(hm, hmt, hist, accum, listcnt, list, (int)capB);
    if(capB){
        k_scan<<<B_*64, 256, 0, stream>>>(list, listcnt, (int)capB, hist,
                                          cntA, cntB, defv, defi, borv, bori);
    } else {
        k_thresh<<<B_, 256, 0, stream>>>(hist, thrbin);
        k_collect<<<TOT_/256, 256, 0, stream>>>(hm, thrbin, cntA, cntB,
                                                defv, defi, borv, bori);
    }
    k_select<<<B_, 256, 0, stream>>>(hm, hmt, wh, reg, tbox, tbid, cntA, cntB,
                                     defv, defi, borv, bori, accum, misc);
    k_regfinal<<<1, 256, 0, stream>>>(wh, reg, wht, regt, mask, ind, accum, misc,
                                      (float*)d_out);
    (void)in_sizes; (void)n_in; (void)out_size;
}